// Round 9
// baseline (262.679 us; speedup 1.0000x reference)
//
#include <hip/hip_runtime.h>

#define COST_CLASS 1.0f
#define COST_BBOX  5.0f
#define COST_GIOU  2.0f
#define EPS 1e-6f

// Problem constants (from setup_inputs): B=32, Q=300, C=11, T=3200
constexpr int kC  = 11;
constexpr int TPB = 64;    // 1 wave per block (800 t4 groups -> 13 blocks/row)
constexpr int NPT = 8;     // preds per inner chunk
constexpr int RB  = 4;     // row-blocks per thread -> 32 preds/thread

typedef float vf4 __attribute__((ext_vector_type(4)));
typedef float vf8 __attribute__((ext_vector_type(8)));

__device__ __forceinline__ float fast_rcp(float x) {
    return __builtin_amdgcn_rcpf(x);   // v_rcp_f32, ~1 ulp — fine vs 0.4 absmax threshold
}

// ---------------- Kernel A: softmax -> TRANSPOSED, pre-folded class cost ----
// probsT[c][n] = 2 - softmax(logits[n])[c]; the 2 folds the GIoU identity
//   (ca-uni)/(ca+EPS) == 1 - (uni+EPS)/(ca+EPS).
__global__ void softmax_probsT_kernel(const float* __restrict__ logits,
                                      float* __restrict__ probsT, int N) {
    int n = blockIdx.x * blockDim.x + threadIdx.x;
    if (n >= N) return;
    float v[kC];
    float m = -1e30f;
#pragma unroll
    for (int c = 0; c < kC; ++c) {
        v[c] = logits[n * kC + c];
        m = fmaxf(m, v[c]);
    }
    float s = 0.f;
#pragma unroll
    for (int c = 0; c < kC; ++c) {
        v[c] = __expf(v[c] - m);
        s += v[c];
    }
    float inv = fast_rcp(s);
#pragma unroll
    for (int c = 0; c < kC; ++c)
        probsT[(size_t)c * N + n] = fmaf(-v[c], inv, 2.0f);   // 2 - prob
}

// ---------------- shared cost-matrix body (R9 trimmed math) ----------------
// Math: cost = (2 - prob) + 5*cb - 2*(inter/U + U/A),  U = uni+EPS, A = ca+EPS
//   inter/U + U/A = (inter*A + U*U) * rcp(U*A)   -> ONE rcp per element.
// REPEAT>1 (verification clone): disjoint row shift N/REPEAT per pass ->
// identical HBM write behavior per pass; per-pass cost = dur/REPEAT.
template<int REPEAT>
__device__ __forceinline__ void cost_body(const float* __restrict__ probsT,
                                          const float* __restrict__ pred_boxes,
                                          const int*   __restrict__ labels,
                                          const float* __restrict__ tboxes,
                                          float* __restrict__ out,
                                          int N, int T) {
    int t4 = blockIdx.x * TPB + threadIdx.x;   // group of 4 targets
    if (t4 >= (T >> 2)) return;
    int tbase = t4 << 2;

    int4 labv = ((const int4*)labels)[t4];
    const int labs[4] = {labv.x, labv.y, labv.z, labv.w};

    // per-thread target state (kept live: amdgpu_waves_per_eu frees the regs)
    float4 tb[4];
    float tx0[4], ty0[4], tx1[4], ty1[4], ta_eps[4];
#pragma unroll
    for (int j = 0; j < 4; ++j) {
        tb[j] = ((const float4*)tboxes)[tbase + j];
        tx0[j] = tb[j].x - 0.5f * tb[j].z;
        ty0[j] = tb[j].y - 0.5f * tb[j].w;
        tx1[j] = tb[j].x + 0.5f * tb[j].z;
        ty1[j] = tb[j].y + 0.5f * tb[j].w;
        ta_eps[j] = fmaf(tb[j].z, tb[j].w, EPS);   // tarea + EPS (w*h exact enough)
    }

#pragma unroll 1
    for (int r = 0; r < REPEAT; ++r) {
        int rshift = (REPEAT > 1) ? r * (N / REPEAT) : 0;   // disjoint rows/pass
#pragma unroll 1
        for (int rb = 0; rb < RB; ++rb) {
            int n0 = blockIdx.y * (NPT * RB) + rb * NPT;
            vf8 ccv[4];
#pragma unroll
            for (int j = 0; j < 4; ++j)
                ccv[j] = *(const vf8*)(probsT + (size_t)labs[j] * N + n0);

#pragma unroll
            for (int i = 0; i < NPT; ++i) {
                int n = n0 + i;
                float4 pb = ((const float4*)pred_boxes)[n];  // wave-uniform
                if constexpr (REPEAT > 1)
                    pb.x += (float)r * 1e-20f;               // per-pass CSE breaker

                float p_x0 = pb.x - 0.5f * pb.z;
                float p_y0 = pb.y - 0.5f * pb.w;
                float p_x1 = pb.x + 0.5f * pb.z;
                float p_y1 = pb.y + 0.5f * pb.w;
                float p_area = pb.z * pb.w;                  // w*h (1 op vs 3)
                float pt[4];                                  // p_area+tarea+EPS
#pragma unroll
                for (int j = 0; j < 4; ++j) pt[j] = p_area + ta_eps[j];

                vf4 res;
#pragma unroll
                for (int j = 0; j < 4; ++j) {
                    // L1 on cxcywh (abs folds into VOP3 input modifiers)
                    float cb = fabsf(pb.x - tb[j].x) + fabsf(pb.y - tb[j].y) +
                               fabsf(pb.z - tb[j].z) + fabsf(pb.w - tb[j].w);
                    // intersection
                    float lt_x = fmaxf(p_x0, tx0[j]), lt_y = fmaxf(p_y0, ty0[j]);
                    float rb_x = fminf(p_x1, tx1[j]), rb_y = fminf(p_y1, ty1[j]);
                    float iw = fmaxf(rb_x - lt_x, 0.f), ih = fmaxf(rb_y - lt_y, 0.f);
                    float inter = iw * ih;
                    float U = pt[j] - inter;                 // union + EPS
                    // enclosure (extents provably >= 0: w,h >= 0)
                    float cx0 = fminf(p_x0, tx0[j]), cy0 = fminf(p_y0, ty0[j]);
                    float cx1 = fmaxf(p_x1, tx1[j]), cy1 = fmaxf(p_y1, ty1[j]);
                    float A = fmaf(cx1 - cx0, cy1 - cy0, EPS);  // carea + EPS
                    // iou + g = (inter*A + U*U) / (U*A): single rcp
                    float num = fmaf(inter, A, U * U);
                    float val = num * fast_rcp(U * A);
                    float rr = fmaf(COST_BBOX, cb, ccv[j][i]);
                    res[j] = fmaf(-2.0f, val, rr);
                }

                int nn = n + rshift;
                if (nn >= N) nn -= N;
                *(vf4*)(out + (size_t)nn * T + tbase) = res;
            }
        }
    }
}

// amdgpu_waves_per_eu(2,4): grid is 3900 waves on 1024 SIMDs (~3.8/SIMD) --
// occupancy >4/EU is unreachable, so let the allocator use regs for ILP
// instead of rematerializing (R8 measured VGPR=60 chosen for 8 waves/EU and
// ~70 VALU ops/elem vs ~35 in source). Raises the budget; no forced clamp.
__global__ __launch_bounds__(TPB)
__attribute__((amdgpu_waves_per_eu(2, 4)))
void cost_matrix_kernel(const float* __restrict__ probsT,
                        const float* __restrict__ pred_boxes,
                        const int*   __restrict__ labels,
                        const float* __restrict__ tboxes,
                        float* __restrict__ out, int N, int T) {
    cost_body<1>(probsT, pred_boxes, labels, tboxes, out, N, T);
}

__global__ __launch_bounds__(TPB)
__attribute__((amdgpu_waves_per_eu(2, 4)))
void cost_matrix_clone4(const float* __restrict__ probsT,
                        const float* __restrict__ pred_boxes,
                        const int*   __restrict__ labels,
                        const float* __restrict__ tboxes,
                        float* __restrict__ out, int N, int T) {
    cost_body<4>(probsT, pred_boxes, labels, tboxes, out, N, T);
}

extern "C" void kernel_launch(void* const* d_in, const int* in_sizes, int n_in,
                              void* d_out, int out_size, void* d_ws, size_t ws_size,
                              hipStream_t stream) {
    const float* class_logits  = (const float*)d_in[0];  // [B,Q,C]
    const float* bbox_coords   = (const float*)d_in[1];  // [B,Q,4]
    const int*   target_labels = (const int*)d_in[2];    // [T]
    const float* target_boxes  = (const float*)d_in[3];  // [T,4]
    float* out = (float*)d_out;

    int N = in_sizes[0] / kC;  // 9600
    int T = in_sizes[2];       // 3200

    float* probsT = (float*)d_ws;                                     // 422 KB
    float* vout   = (float*)((char*)d_ws + (size_t)16 * 1024 * 1024); // 122.9 MB

    {
        int tpb = 256;
        int blocks = (N + tpb - 1) / tpb;
        softmax_probsT_kernel<<<blocks, tpb, 0, stream>>>(class_logits, probsT, N);
    }

    dim3 grid((T / 4 + TPB - 1) / TPB, N / (NPT * RB));

    // Verification clone: 4x production body, disjoint writes (shift N/4).
    // Sanity: its WRITE_SIZE must be ~491,520 KB. per-pass = dur/4.
    if (ws_size >= (size_t)160 * 1024 * 1024) {
        cost_matrix_clone4<<<grid, TPB, 0, stream>>>(probsT, bbox_coords,
            target_labels, target_boxes, vout, N, T);
    }

    // Kernel of record.
    cost_matrix_kernel<<<grid, TPB, 0, stream>>>(probsT, bbox_coords,
        target_labels, target_boxes, out, N, T);
}

// Round 10
// 150.666 us; speedup vs baseline: 1.7435x; 1.7435x over previous
//
#include <hip/hip_runtime.h>

#define COST_CLASS 1.0f
#define COST_BBOX  5.0f
#define COST_GIOU  2.0f
#define EPS 1e-6f

// Problem constants (from setup_inputs): B=32, Q=300, C=11, T=3200
constexpr int kC  = 11;
constexpr int TPB = 64;    // 1 wave per block (800 t4 groups -> 13 blocks/row)
constexpr int NPT = 8;     // preds per inner chunk
constexpr int RB  = 4;     // row-blocks per thread -> 32 preds/thread

typedef float vf4 __attribute__((ext_vector_type(4)));
typedef float vf8 __attribute__((ext_vector_type(8)));

__device__ __forceinline__ float fast_rcp(float x) {
    return __builtin_amdgcn_rcpf(x);   // v_rcp_f32, ~1 ulp — fine vs 0.4 absmax threshold
}

// ---------------- Kernel A: softmax -> TRANSPOSED, pre-folded class cost ----
// probsT[c][n] = 2 - softmax(logits[n])[c]; the 2 folds the GIoU identity
//   (ca-uni)/(ca+EPS) == 1 - (uni+EPS)/(ca+EPS).
__global__ void softmax_probsT_kernel(const float* __restrict__ logits,
                                      float* __restrict__ probsT, int N) {
    int n = blockIdx.x * blockDim.x + threadIdx.x;
    if (n >= N) return;
    float v[kC];
    float m = -1e30f;
#pragma unroll
    for (int c = 0; c < kC; ++c) {
        v[c] = logits[n * kC + c];
        m = fmaxf(m, v[c]);
    }
    float s = 0.f;
#pragma unroll
    for (int c = 0; c < kC; ++c) {
        v[c] = __expf(v[c] - m);
        s += v[c];
    }
    float inv = fast_rcp(s);
#pragma unroll
    for (int c = 0; c < kC; ++c)
        probsT[(size_t)c * N + n] = fmaf(-v[c], inv, 2.0f);   // 2 - prob
}

// ---------------- Kernel B: cost matrix, store/compute overlap -------------
// R10 theory (from R8/R9 clean clones): per-pass 33.7us == compute 16 + store
// 18.8 SUMMED, because vmcnt is a single IN-ORDER counter for loads AND
// stores: each rb's ccv loads were issued AFTER the previous rb's 8 stores,
// so waiting for ccv drained the store burst -> serial pipes.
// Fix: ping-pong prefetch. Issue rb+1's ccv loads at the TOP of the body,
// BEFORE rb's stores. The ccv wait becomes vmcnt(<=8) with only the YOUNGER
// stores outstanding -> stores drain under the next rb's compute.
__global__ __launch_bounds__(TPB)
__attribute__((amdgpu_waves_per_eu(2, 4)))
void cost_matrix_kernel(const float* __restrict__ probsT,      // [C,N] (=2-prob)
                        const float* __restrict__ pred_boxes,  // [N,4] cxcywh
                        const int*   __restrict__ labels,      // [T]
                        const float* __restrict__ tboxes,      // [T,4] cxcywh
                        float* __restrict__ out,               // [N,T]
                        int N, int T) {
    int t4 = blockIdx.x * TPB + threadIdx.x;   // group of 4 targets
    if (t4 >= (T >> 2)) return;
    int tbase = t4 << 2;

    int4 labv = ((const int4*)labels)[t4];
    const int labs[4] = {labv.x, labv.y, labv.z, labv.w};

    // per-thread target state, live across all 32 preds
    float4 tb[4];
    float tx0[4], ty0[4], tx1[4], ty1[4], ta_eps[4];
#pragma unroll
    for (int j = 0; j < 4; ++j) {
        tb[j] = ((const float4*)tboxes)[tbase + j];
        tx0[j] = tb[j].x - 0.5f * tb[j].z;
        ty0[j] = tb[j].y - 0.5f * tb[j].w;
        tx1[j] = tb[j].x + 0.5f * tb[j].z;
        ty1[j] = tb[j].y + 0.5f * tb[j].w;
        ta_eps[j] = fmaf(tb[j].z, tb[j].w, EPS);   // tarea + EPS
    }

    int n0base = blockIdx.y * (NPT * RB);

    // one rb-step: prefetch ccv for n0pre into ccp (issued FIRST -> older than
    // this step's stores), then compute+store rows n0rb..n0rb+7 from ccu.
    auto step = [&](const vf8 (&ccu)[4], vf8 (&ccp)[4], int n0rb, int n0pre) {
#pragma unroll
        for (int j = 0; j < 4; ++j)
            ccp[j] = *(const vf8*)(probsT + (size_t)labs[j] * N + n0pre);

#pragma unroll
        for (int i = 0; i < NPT; ++i) {
            int n = n0rb + i;
            float4 pb = ((const float4*)pred_boxes)[n];  // block-uniform -> s_load
            float p_x0 = pb.x - 0.5f * pb.z;
            float p_y0 = pb.y - 0.5f * pb.w;
            float p_x1 = pb.x + 0.5f * pb.z;
            float p_y1 = pb.y + 0.5f * pb.w;
            float p_area = pb.z * pb.w;

            vf4 res;
#pragma unroll
            for (int j = 0; j < 4; ++j) {
                // L1 on cxcywh (abs folds into VOP3 input modifiers)
                float cb = fabsf(pb.x - tb[j].x) + fabsf(pb.y - tb[j].y) +
                           fabsf(pb.z - tb[j].z) + fabsf(pb.w - tb[j].w);
                // intersection
                float lt_x = fmaxf(p_x0, tx0[j]), lt_y = fmaxf(p_y0, ty0[j]);
                float rb_x = fminf(p_x1, tx1[j]), rb_y = fminf(p_y1, ty1[j]);
                float iw = fmaxf(rb_x - lt_x, 0.f), ih = fmaxf(rb_y - lt_y, 0.f);
                float inter = iw * ih;
                float U = (p_area + ta_eps[j]) - inter;      // union + EPS
                // enclosure (extents provably >= 0: boxes have w,h >= 0)
                float cx0 = fminf(p_x0, tx0[j]), cy0 = fminf(p_y0, ty0[j]);
                float cx1 = fmaxf(p_x1, tx1[j]), cy1 = fmaxf(p_y1, ty1[j]);
                float A = fmaf(cx1 - cx0, cy1 - cy0, EPS);   // carea + EPS
                // iou + g = (inter*A + U*U) / (U*A): single rcp per element
                float num = fmaf(inter, A, U * U);
                float val = num * fast_rcp(U * A);
                float rr = fmaf(COST_BBOX, cb, ccu[j][i]);
                res[j] = fmaf(-2.0f, val, rr);
            }
            *(vf4*)(out + (size_t)n * T + tbase) = res;
        }
    };

    vf8 ccvA[4], ccvB[4];
    // prologue: load rb=0 into A
#pragma unroll
    for (int j = 0; j < 4; ++j)
        ccvA[j] = *(const vf8*)(probsT + (size_t)labs[j] * N + n0base);

    // RB=4 as two ping-pong double-steps (no mov-swap, all static indexing)
#pragma unroll 1
    for (int rb2 = 0; rb2 < RB; rb2 += 2) {
        int n0a = n0base + rb2 * NPT;
        int n0b = n0a + NPT;
        int n0c = (rb2 + 2 < RB) ? n0b + NPT : n0b;   // clamp: last prefetch benign
        step(ccvA, ccvB, n0a, n0b);   // compute rb2   from A, prefetch rb2+1 -> B
        step(ccvB, ccvA, n0b, n0c);   // compute rb2+1 from B, prefetch rb2+2 -> A
    }
}

extern "C" void kernel_launch(void* const* d_in, const int* in_sizes, int n_in,
                              void* d_out, int out_size, void* d_ws, size_t ws_size,
                              hipStream_t stream) {
    const float* class_logits  = (const float*)d_in[0];  // [B,Q,C]
    const float* bbox_coords   = (const float*)d_in[1];  // [B,Q,4]
    const int*   target_labels = (const int*)d_in[2];    // [T]
    const float* target_boxes  = (const float*)d_in[3];  // [T,4]
    float* out = (float*)d_out;

    int N = in_sizes[0] / kC;  // 9600
    int T = in_sizes[2];       // 3200

    float* probsT = (float*)d_ws;   // C*N floats = 422 KB, fully overwritten

    {
        int tpb = 256;
        int blocks = (N + tpb - 1) / tpb;
        softmax_probsT_kernel<<<blocks, tpb, 0, stream>>>(class_logits, probsT, N);
    }
    {
        dim3 grid((T / 4 + TPB - 1) / TPB, N / (NPT * RB));
        cost_matrix_kernel<<<grid, TPB, 0, stream>>>(probsT, bbox_coords,
                                                     target_labels, target_boxes,
                                                     out, N, T);
    }
}